// Round 16
// baseline (181.573 us; speedup 1.0000x reference)
//
#include <hip/hip_runtime.h>
#include <hip/hip_bf16.h>

typedef __attribute__((ext_vector_type(8))) short s16x8;
typedef __attribute__((ext_vector_type(4))) short s16x4;
typedef __attribute__((ext_vector_type(4))) float f32x4;

#if __has_builtin(__builtin_amdgcn_exp2f)
#define EXP2F(x) __builtin_amdgcn_exp2f(x)
#else
#define EXP2F(x) exp2f(x)
#endif

#define EMB   512
#define MROWS 8192   // S*B

// RNE — epilogues / weight convert
__device__ __forceinline__ short f2bf(float f) {
    union { float f; unsigned u; } z; z.f = f;
    unsigned r = z.u + 0x7FFF + ((z.u >> 16) & 1);
    return (short)(r >> 16);
}
// fast round-half-away (2 VALU ops) — GEMM staging commits
__device__ __forceinline__ short f2bf_fast(float f) {
    union { float f; unsigned u; } z; z.f = f;
    return (short)((z.u + 0x8000u) >> 16);
}
// native cast — compiler lowers to v_cvt_pk_bf16_f32-class code (m240)
__device__ __forceinline__ short f2bf_cvt(float f) {
    union { __hip_bfloat16 h; short s; } cv;
    cv.h = __float2bfloat16(f);
    return cv.s;
}
// 16B-slot XOR swizzle (involution): conflict-free ds_read AND ds_write
// (used by the fp32-operand register staging path only)
__device__ __forceinline__ int swzs(int s) { return s ^ ((s >> 3) & 7); }

// Barrier WITHOUT the vmcnt(0) drain (r7 win) — flash / epilogues.
__device__ __forceinline__ void barrier_fast() {
    asm volatile("s_waitcnt lgkmcnt(0)" ::: "memory");
    __builtin_amdgcn_s_barrier();
    __builtin_amdgcn_sched_barrier(0);
}
// GEMM-mainloop barrier: vmcnt(4) forces this step's 2 global_load_lds DMAs
// complete in EVERY wave before the barrier releases readers (issue order is
// gld x2 then fp32-loads x4, so <=4 outstanding == DMA done).  Cross-wave
// DMA visibility must be established BEFORE the barrier — a per-wave wait at
// read time would not cover other waves' DMA (m104-class hazard).
__device__ __forceinline__ void barrier_gld() {
    asm volatile("s_waitcnt vmcnt(4) lgkmcnt(0)" ::: "memory");
    __builtin_amdgcn_s_barrier();
    __builtin_amdgcn_sched_barrier(0);
}

// direct global->LDS DMA, 16B per lane; dst is the WAVE-UNIFORM base (HW adds
// lane*16).  Per-lane src carries the fragment permutation (m173 pattern).
__device__ __forceinline__ void gld16(const short* src, short* dst) {
    __builtin_amdgcn_global_load_lds(
        (const __attribute__((address_space(1))) void*)src,
        (__attribute__((address_space(3))) void*)dst, 16, 0, 0);
}

// ---------------------------------------------------------------------------
// Kernel 0: in_proj weight fp32 -> bf16 into the unused region of d_out
// (vt occupies [0,8MB); wb at [8MB,9.5MB); both dead before out_proj writes).
// ---------------------------------------------------------------------------
__global__ __launch_bounds__(256) void w_to_bf16(const float* __restrict__ W,
                                                 short* __restrict__ wb, int n)
{
    int i = (blockIdx.x * 256 + threadIdx.x) * 8;
    if (i < n) {
        f32x4 a = *(const f32x4*)(W + i);
        f32x4 b = *(const f32x4*)(W + i + 4);
        s16x8 o;
        o[0] = f2bf(a[0]); o[1] = f2bf(a[1]); o[2] = f2bf(a[2]); o[3] = f2bf(a[3]);
        o[4] = f2bf(b[0]); o[5] = f2bf(b[1]); o[6] = f2bf(b[2]); o[7] = f2bf(b[3]);
        *(s16x8*)(wb + i) = o;
    }
}

// ---------------------------------------------------------------------------
// BT-GEMM mainloop v18: BK=64, 512 threads = 8 waves, tile 128x128,
// 16 MFMA/wave/step, double-buffered 64KB LDS, 1 barrier/step.
//  - fp32 operand: 2-deep register pipeline + swzs fragment-linear LDS
//    (proven r11/r13; commit writes and lsw reads both bank-floor).
//  - bf16 operand: __builtin_amdgcn_global_load_lds direct DMA into LINEAR
//    fragment slots (slot = h*4096 + tile*512 + lane*8 shorts) — no ds_write,
//    no staging VGPRs, stride-1 reads (conflict-free without swizzle).
//    Wave wv stages chunks c = 2wv+p: h=c>>3, t=c&7; lane source
//    row = t*16+(lane&15), col = kt + h*32 + (lane>>4)*8  (64B/row segments,
//    the m97-proven shape).  DMA for tile n+1 issues at step-n top (its
//    buffer's readers finished at barrier n-1); barrier_gld's vmcnt(4)
//    guarantees completion before barrier n releases step-n+1 readers.
// AGLD=0: A fp32(reg), B bf16(gld)  [qkv].  AGLD=1: A bf16(gld), B fp32(reg).
// r14 lesson retained: no occupancy forcing (2 blocks/CU structural).
// ---------------------------------------------------------------------------
template<int AGLD>
__device__ __forceinline__ void gemm_mainloop(const void* __restrict__ Ag,
                                              const void* __restrict__ Bg,
                                              short* sA, short* sB,
                                              f32x4 acc[2][4], int ld, int Klen)
{
    const int tid  = threadIdx.x;          // 0..511
    const int lane = tid & 63;
    const int wv   = tid >> 6;             // 0..7
    const int lsw  = lane ^ ((lane >> 3) & 7);
    const int amt  = (wv >> 1) * 2;        // A m-tile base (0,2,4,6)
    const int bnt  = (wv & 1) * 4;         // B n-tile base (0,4)

    // operand routing
    const float* rG = (const float*)(AGLD ? Bg : Ag);   // fp32 operand
    const short* gG = (const short*)(AGLD ? Ag : Bg);   // bf16 operand
    short* sR = AGLD ? sB : sA;
    short* sG = AGLD ? sA : sB;

    // fp32 staging geometry (proven r11)
    const int srow = tid >> 3, qd = tid & 7;   // rows srow, srow+64; chunk qd
    const int offL = (qd >> 2) * 4096
                   + swzs((srow >> 4) * 64 + (qd & 3) * 16 + (srow & 15)) * 8;
    const int offH = (qd >> 2) * 4096
                   + swzs(((srow >> 4) + 4) * 64 + (qd & 3) * 16 + (srow & 15)) * 8;

    // gld geometry: wave wv owns chunks c0 = 2wv, c1 = 2wv+1
    const int c0 = wv * 2, c1 = wv * 2 + 1;
    const short* gsrc0 = gG + (size_t)((c0 & 7) * 16 + (lane & 15)) * ld
                       + (c0 >> 3) * 32 + (lane >> 4) * 8;
    const short* gsrc1 = gG + (size_t)((c1 & 7) * 16 + (lane & 15)) * ld
                       + (c1 >> 3) * 32 + (lane >> 4) * 8;
    const int gdst0 = (c0 >> 3) * 4096 + (c0 & 7) * 512;   // wave-uniform bases
    const int gdst1 = (c1 >> 3) * 4096 + (c1 & 7) * 512;

    f32x4 F0[4], F1[4];   // fp32 staging frames (2-deep)

    auto loadR = [&](int kt, f32x4 fr[4]) {
        const float* g = rG + (size_t)srow * ld + kt + qd * 8;
        fr[0] = *(const f32x4*)g;
        fr[1] = *(const f32x4*)(g + 4);
        fr[2] = *(const f32x4*)(g + (size_t)64 * ld);
        fr[3] = *(const f32x4*)(g + (size_t)64 * ld + 4);
    };
    auto commitR = [&](short* s, f32x4 fr[4]) {
        s16x8 o;
        o[0] = f2bf_fast(fr[0][0]); o[1] = f2bf_fast(fr[0][1]);
        o[2] = f2bf_fast(fr[0][2]); o[3] = f2bf_fast(fr[0][3]);
        o[4] = f2bf_fast(fr[1][0]); o[5] = f2bf_fast(fr[1][1]);
        o[6] = f2bf_fast(fr[1][2]); o[7] = f2bf_fast(fr[1][3]);
        *(s16x8*)(s + offL) = o;
        o[0] = f2bf_fast(fr[2][0]); o[1] = f2bf_fast(fr[2][1]);
        o[2] = f2bf_fast(fr[2][2]); o[3] = f2bf_fast(fr[2][3]);
        o[4] = f2bf_fast(fr[3][0]); o[5] = f2bf_fast(fr[3][1]);
        o[6] = f2bf_fast(fr[3][2]); o[7] = f2bf_fast(fr[3][3]);
        *(s16x8*)(s + offH) = o;
    };
    auto gldT = [&](int kt, int buf) {
        gld16(gsrc0 + kt, sG + buf * 8192 + gdst0);
        gld16(gsrc1 + kt, sG + buf * 8192 + gdst1);
    };
    auto compute = [&](int buf) {
        const short* sRc = sR + buf * 8192;
        const short* sGc = sG + buf * 8192;
#pragma unroll
        for (int h = 0; h < 2; ++h) {      // two K=32 halves
            s16x8 a[2], b[4];
            if (AGLD) {
#pragma unroll
                for (int i = 0; i < 2; ++i)
                    a[i] = *(const s16x8*)(sGc + h * 4096 + (amt + i) * 512 + lane * 8);
#pragma unroll
                for (int j = 0; j < 4; ++j)
                    b[j] = *(const s16x8*)(sRc + h * 4096 + ((bnt + j) * 64 + lsw) * 8);
            } else {
#pragma unroll
                for (int i = 0; i < 2; ++i)
                    a[i] = *(const s16x8*)(sRc + h * 4096 + ((amt + i) * 64 + lsw) * 8);
#pragma unroll
                for (int j = 0; j < 4; ++j)
                    b[j] = *(const s16x8*)(sGc + h * 4096 + (bnt + j) * 512 + lane * 8);
            }
#pragma unroll
            for (int i = 0; i < 2; ++i)
#pragma unroll
                for (int j = 0; j < 4; ++j)
                    acc[i][j] = __builtin_amdgcn_mfma_f32_16x16x32_bf16(a[i], b[j], acc[i][j], 0, 0, 0);
        }
    };

    // prologue: gld tile 0 -> buf0 FIRST (oldest in vmcnt queue), then fp32
    // frames for tiles 0,64; commit tile 0.  barrier_gld's vmcnt(4) leaves
    // only F1's 4 loads outstanding -> DMA forced complete.
    gldT(0, 0);
    loadR(0, F0);
    loadR(64, F1);
    commitR(sR, F0);
    barrier_gld();

    for (int kt = 0; kt < Klen; kt += 128) {
        // even step: read buf0 (tile kt); gld tile kt+64 -> buf1;
        // fp32 tile kt+128 -> F0; commit tile kt+64 (F1) -> buf1.
        const int k2 = (kt + 128 < Klen) ? kt + 128 : 0;   // wrap: dead load
        gldT((kt + 64 < Klen) ? kt + 64 : 0, 1);
        loadR(k2, F0);
        compute(0);
        commitR(sR + 8192, F1);
        barrier_gld();
        // odd step: read buf1 (tile kt+64); gld tile kt+128 -> buf0;
        // fp32 tile kt+192 -> F1; commit tile kt+128 (F0) -> buf0.
        const int k3 = (kt + 192 < Klen) ? kt + 192 : 0;
        gldT(k2, 0);
        loadR(k3, F1);
        compute(1);
        commitR(sR, F0);
        barrier_gld();
    }
    // all DMAs drained by the final barrier_gld's vmcnt(4) -> safe for the
    // caller to reuse LDS (epilogue C-staging).
}

// ---------------------------------------------------------------------------
// Kernel 1 (v18): fused QKV projection.  A = X fp32 (reg), B = wb bf16 (gld).
// ---------------------------------------------------------------------------
__global__ __launch_bounds__(512, 4) void qkv_proj(const float* __restrict__ query,
                                                   const float* __restrict__ key,
                                                   const float* __restrict__ value,
                                                   const short* __restrict__ wb,
                                                   const float* __restrict__ bias,
                                                   short* __restrict__ q,
                                                   short* __restrict__ k,
                                                   short* __restrict__ vt)
{
    __shared__ __align__(16) short smem[32768];   // 64KB: A dbuf | B dbuf
    short* sA = smem;            // 2 x 8192
    short* sB = smem + 16384;    // 2 x 8192

    const int z = blockIdx.z;
    const float* X  = (z == 0) ? query : (z == 1) ? key : value;
    const short* Wz = wb   + (z == 2 ? (size_t)1024 * EMB : 0);
    const float* bz = bias + (z == 2 ? 1024 : 0);
    const float scale = (z == 0) ? 0.125f * 1.44269504f : 1.0f;

    const int blockM = blockIdx.x * 128, blockN = blockIdx.y * 128;

    f32x4 acc[2][4];
#pragma unroll
    for (int i = 0; i < 2; ++i)
#pragma unroll
        for (int j = 0; j < 4; ++j)
            acc[i][j] = (f32x4){0.f, 0.f, 0.f, 0.f};

    gemm_mainloop<0>(X + (size_t)blockM * EMB, Wz + (size_t)blockN * EMB,
                     sA, sB, acc, EMB, EMB);

    const int tid = threadIdx.x, lane = tid & 63, wv = tid >> 6;
    const int l15 = lane & 15, quad = lane >> 4;
    const int wm = (wv >> 1) * 32, wn = (wv & 1) * 64;

    // ---- stage C-tile into LDS in output order (bf16, RNE) ----
#pragma unroll
    for (int j = 0; j < 4; ++j) {
        int colL = wn + j * 16 + l15;          // 0..127
        float bval = bz[blockN + colL];
        int hL = colL >> 6, hd = colL & 63;
#pragma unroll
        for (int i = 0; i < 2; ++i) {
#pragma unroll
            for (int r = 0; r < 4; ++r) {
                int rowL = wm + i * 16 + quad * 4 + r;   // 0..127
                int b = rowL & 3, sp = rowL >> 2;
                float val = (acc[i][j][r] + bval) * scale;
                int idx;
                if (z == 2) {
                    int R = (b * 2 + hL) * 64 + hd;
                    idx = R * 32 + (((sp >> 3) ^ (R & 3)) << 3) + (sp & 7);
                } else {
                    idx = ((b * 2 + hL) * 32 + sp) * 64 + hd;
                }
                smem[idx] = f2bf(val);
            }
        }
    }
    barrier_fast();

    // ---- coalesced stores: thread t owns shorts [t*32, t*32+32) ----
    if (z == 2) {
        int R = tid;
        int b = tid >> 7, hL = (tid >> 6) & 1, hd = tid & 63;
        int h = (blockN >> 6) + hL;
        short* dst = vt + ((size_t)(b * 8 + h) * 64 + hd) * 2048 + (blockM >> 2);
#pragma unroll
        for (int u = 0; u < 4; ++u)
            ((s16x8*)dst)[u] = *(const s16x8*)(smem + R * 32 + ((u ^ (R & 3)) << 3));
    } else {
        const s16x8* src = (const s16x8*)(smem + tid * 32);
        int b = tid >> 7, hL = (tid >> 6) & 1;
        int sp = (tid >> 1) & 31, hdh = (tid & 1) * 32;
        int h = (blockN >> 6) + hL;
        short* dstp = (z == 0) ? q : k;
        short* dst = dstp + ((size_t)(b * 8 + h) * 2048 + (blockM >> 2) + sp) * 64 + hdh;
#pragma unroll
        for (int u = 0; u < 4; ++u) ((s16x8*)dst)[u] = src[u];
    }
}

// ---------------------------------------------------------------------------
// Kernel 2 (r12/r13-proven 42.5us, untouched): flash attention — 512 threads
// / 256 blocks (grid 32x8), 8 waves share one 64KB K/V double-buffer.
// Q pre-scaled by log2(e)/8 so p = exp2(s').
// ---------------------------------------------------------------------------
__global__ __launch_bounds__(512, 2) void flash_attn(const short* __restrict__ q,
                                                     const short* __restrict__ k,
                                                     const short* __restrict__ vt,
                                                     short* __restrict__ attn)
{
    __shared__ __align__(16) short sK[2][8192];   // [buf][sub(4096) | half(2048) | slots]
    __shared__ __align__(16) short sV[2][8192];
    const int bh = blockIdx.x;            // fast grid dim -> XCD locality
    const int q0 = blockIdx.y * 256;
    const int tid = threadIdx.x, wv = tid >> 6, lane = tid & 63;
    const int l15 = lane & 15, quad = lane >> 4;
    const int lsw = lane ^ ((lane >> 3) & 7);

    // Q fragments: 2 sub-tiles (qr) x 2 K-halves; rows q0 + wv*32 + qr*16 + l15
    s16x8 qf[2][2];
#pragma unroll
    for (int qr = 0; qr < 2; ++qr) {
        const short* qp = q + ((size_t)(bh * 2048 + q0 + wv * 32 + qr * 16 + l15)) * 64 + quad * 8;
        qf[qr][0] = *(const s16x8*)qp;
        qf[qr][1] = *(const s16x8*)(qp + 32);
    }

    const short* kg = k  + (size_t)bh * 2048 * 64;   // + (kt+key)*64 + hd
    const short* vg = vt + (size_t)bh * 64 * 2048;   // + hd*2048 + kt + key

    // staging: thread (tL = tid&255, sub = tid>>8); rk = tL>>2, qd = tL&3
    const int tL = tid & 255, sub = tid >> 8;
    const int rk = tL >> 2, qd = tL & 3;
    const int pr = (rk & 35) | ((rk & 24) >> 1) | ((rk & 4) << 2);
    const int kw0 = sub * 4096 + swzs((pr >> 4) * 64 + qd * 16 + (pr & 15)) * 8;
    const int vw0 = sub * 4096 + swzs((rk >> 4) * 64 + qd * 16 + (rk & 15)) * 8;
    const short* kgt = kg + (size_t)(sub * 64 + rk) * 64 + qd * 8;
    const short* vgt = vg + (size_t)rk * 2048 + sub * 64 + qd * 8;

    f32x4 o[2][4];
    float ls[2][4];
#pragma unroll
    for (int qr = 0; qr < 2; ++qr)
#pragma unroll
        for (int i = 0; i < 4; ++i) { o[qr][i] = (f32x4){0.f, 0.f, 0.f, 0.f}; ls[qr][i] = 0.f; }

    // staging regs: this thread's sub only
    s16x8 kA, kB, vA, vB;
    auto loadT = [&](int kt) {           // kt = base of 128-key tile
        kA = *(const s16x8*)(kgt + (size_t)kt * 64);
        kB = *(const s16x8*)(kgt + (size_t)kt * 64 + 32);
        vA = *(const s16x8*)(vgt + kt);
        vB = *(const s16x8*)(vgt + kt + 32);
    };
    auto commitT = [&](int buf) {
        *(s16x8*)(sK[buf] + kw0)        = kA;
        *(s16x8*)(sK[buf] + kw0 + 2048) = kB;
        *(s16x8*)(sV[buf] + vw0)        = vA;
        *(s16x8*)(sV[buf] + vw0 + 2048) = vB;
    };
    auto computeQK = [&](const short* Kc, f32x4 sc[2][4]) {
#pragma unroll
        for (int ct = 0; ct < 4; ++ct) {
            s16x8 kf0 = *(const s16x8*)(Kc + (ct * 64 + lsw) * 8);
            s16x8 kf1 = *(const s16x8*)(Kc + (ct * 64 + lsw) * 8 + 2048);
#pragma unroll
            for (int qr = 0; qr < 2; ++qr) {
                f32x4 c = (f32x4){0.f, 0.f, 0.f, 0.f};
                c = __builtin_amdgcn_mfma_f32_16x16x32_bf16(kf0, qf[qr][0], c, 0, 0, 0);
                c = __builtin_amdgcn_mfma_f32_16x16x32_bf16(kf1, qf[qr][1], c, 0, 0, 0);
                sc[qr][ct] = c;
            }
        }
    };
    auto softmaxPV = [&](f32x4 sc[2][4], const short* Vc) {
        s16x8 pf[2][2];
#pragma unroll
        for (int qr = 0; qr < 2; ++qr)
#pragma unroll
            for (int c = 0; c < 2; ++c)
#pragma unroll
                for (int h = 0; h < 2; ++h)
#pragma unroll
                    for (int r = 0; r < 4; ++r) {
                        float p = EXP2F(sc[qr][2 * c + h][r]);
                        ls[qr][r] += p;
                        pf[qr][c][h * 4 + r] = f2bf_cvt(p);
                    }
#pragma unroll
        for (int nt = 0; nt < 4; ++nt)
#pragma unroll
            for (int c = 0; c < 2; ++c) {
                s16x8 vf = *(const s16x8*)(Vc + ((c * 4 + nt) * 64 + lsw) * 8);
#pragma unroll
                for (int qr = 0; qr < 2; ++qr)
                    o[qr][nt] = __builtin_amdgcn_mfma_f32_16x16x32_bf16(pf[qr][c], vf, o[qr][nt], 0, 0, 0);
            }
    };

    loadT(0);
    commitT(0);
    __syncthreads();

    int cur = 0;
    for (int kt = 0; kt < 2048; kt += 128) {
        loadT((kt + 128) & 2047);        // wraps on last iter (harmless)

        f32x4 sc0[2][4], sc1[2][4];
        computeQK(sK[cur], sc0);
        computeQK(sK[cur] + 4096, sc1);  // independent of sc0's softmax
        softmaxPV(sc0, sV[cur]);         // VALU overlaps sc1's MFMAs
        softmaxPV(sc1, sV[cur] + 4096);  // sub1 softmax overlaps sub0 PV

        commitT(cur ^ 1);
        __syncthreads();
        cur ^= 1;
    }

    const int b = bh >> 3, h = bh & 7;
#pragma unroll
    for (int qr = 0; qr < 2; ++qr) {
        float s = ls[qr][0] + ls[qr][1] + ls[qr][2] + ls[qr][3];
        s += __shfl_xor(s, 16, 64);
        s += __shfl_xor(s, 32, 64);
        float sinv = 1.0f / s;
        float inv[4];
#pragma unroll
        for (int r = 0; r < 4; ++r)
            inv[r] = __shfl(sinv, quad * 20 + r, 64);
#pragma unroll
        for (int r = 0; r < 4; ++r) {
            int srow = q0 + wv * 32 + qr * 16 + quad * 4 + r;
#pragma unroll
            for (int nt = 0; nt < 4; ++nt)
                attn[(size_t)(srow * 4 + b) * 512 + h * 64 + nt * 16 + l15] = f2bf(o[qr][nt][r] * inv[r]);
        }
    }
}

// ---------------------------------------------------------------------------
// Kernel 3 (v18): output projection.  A = attn bf16 (gld), B = W fp32 (reg).
// ---------------------------------------------------------------------------
__global__ __launch_bounds__(512, 4) void out_proj(const short* __restrict__ attn,
                                                   const float* __restrict__ W,
                                                   const float* __restrict__ bias,
                                                   float* __restrict__ out)
{
    __shared__ __align__(16) short smem[32768];   // 64KB: A dbuf | B dbuf
    short* sA = smem;
    short* sB = smem + 16384;
    const int blockM = blockIdx.x * 128, blockN = blockIdx.y * 128;

    f32x4 acc[2][4];
#pragma unroll
    for (int i = 0; i < 2; ++i)
#pragma unroll
        for (int j = 0; j < 4; ++j)
            acc[i][j] = (f32x4){0.f, 0.f, 0.f, 0.f};

    gemm_mainloop<1>(attn + (size_t)blockM * EMB, W + (size_t)blockN * EMB,
                     sA, sB, acc, EMB, EMB);

    const int tid = threadIdx.x, lane = tid & 63, wv = tid >> 6;
    const int l15 = lane & 15, quad = lane >> 4;
    const int wm = (wv >> 1) * 32, wn = (wv & 1) * 64;

#pragma unroll
    for (int j = 0; j < 4; ++j) {
        int col = blockN + wn + j * 16 + l15;
        float bval = bias[col];
#pragma unroll
        for (int i = 0; i < 2; ++i) {
#pragma unroll
            for (int r = 0; r < 4; ++r) {
                int row = blockM + wm + i * 16 + quad * 4 + r;
                out[(size_t)row * 512 + col] = acc[i][j][r] + bval;
            }
        }
    }
}

// ---------------------------------------------------------------------------
// Dtype contract: inputs FP32, output FP32. Internals bf16.
// 4 dispatches:
//   w_to_bf16:  in_proj W fp32 -> bf16 wb (d_out+8MB, dead before out_proj)
//   qkv_proj:   fp32 X + bf16 W -> bf16 q,k (ws) + V^T into d_out[0..8MB)
//   flash_attn: q, k, d_out(V^T) -> attn (ws+16MB)
//   out_proj:   attn + fp32 W_out -> d_out (fp32 final, overwrites scratch)
// ---------------------------------------------------------------------------
extern "C" void kernel_launch(void* const* d_in, const int* in_sizes, int n_in,
                              void* d_out, int out_size, void* d_ws, size_t ws_size,
                              hipStream_t stream)
{
    const float* query = (const float*)d_in[0];
    const float* key   = (const float*)d_in[1];
    const float* value = (const float*)d_in[2];
    const float* ipw   = (const float*)d_in[3];   // (1536, 512)
    const float* ipb   = (const float*)d_in[4];   // (1536,)
    const float* opw   = (const float*)d_in[5];   // (512, 512)
    const float* opb   = (const float*)d_in[6];   // (512,)
    float* out = (float*)d_out;

    const size_t NELEM = (size_t)MROWS * EMB;     // 4,194,304 elements
    short* q    = (short*)d_ws;
    short* k    = q + NELEM;
    short* attn = k + NELEM;
    short* vt   = (short*)d_out;                  // [0 .. 8MB) of d_out
    short* wb   = (short*)d_out + NELEM;          // [8MB .. 9.5MB) of d_out

    w_to_bf16 <<<dim3(384),      256, 0, stream>>>(ipw, wb, 1536 * EMB);
    qkv_proj  <<<dim3(64, 4, 3), 512, 0, stream>>>(query, key, value, wb, ipb, q, k, vt);
    flash_attn<<<dim3(32, 8),    512, 0, stream>>>(q, k, vt, attn);
    out_proj  <<<dim3(64, 4),    512, 0, stream>>>(attn, opw, opb, out);
}

// Round 17
// 171.705 us; speedup vs baseline: 1.0575x; 1.0575x over previous
//
#include <hip/hip_runtime.h>
#include <hip/hip_bf16.h>

typedef __attribute__((ext_vector_type(8))) short s16x8;
typedef __attribute__((ext_vector_type(4))) short s16x4;
typedef __attribute__((ext_vector_type(4))) float f32x4;

#if __has_builtin(__builtin_amdgcn_exp2f)
#define EXP2F(x) __builtin_amdgcn_exp2f(x)
#else
#define EXP2F(x) exp2f(x)
#endif

#define EMB   512
#define MROWS 8192   // S*B

// RNE — epilogues / weight convert
__device__ __forceinline__ short f2bf(float f) {
    union { float f; unsigned u; } z; z.f = f;
    unsigned r = z.u + 0x7FFF + ((z.u >> 16) & 1);
    return (short)(r >> 16);
}
// fast round-half-away (2 VALU ops) — GEMM staging commits
__device__ __forceinline__ short f2bf_fast(float f) {
    union { float f; unsigned u; } z; z.f = f;
    return (short)((z.u + 0x8000u) >> 16);
}
// native cast — compiler lowers to v_cvt_pk_bf16_f32-class code (m240)
__device__ __forceinline__ short f2bf_cvt(float f) {
    union { __hip_bfloat16 h; short s; } cv;
    cv.h = __float2bfloat16(f);
    return cv.s;
}
// 16B-slot XOR swizzle (involution): conflict-free ds_read AND ds_write
__device__ __forceinline__ int swzs(int s) { return s ^ ((s >> 3) & 7); }

// Barrier WITHOUT the vmcnt(0) drain (GEMM mainloops — r7 win).
__device__ __forceinline__ void barrier_fast() {
    asm volatile("s_waitcnt lgkmcnt(0)" ::: "memory");
    __builtin_amdgcn_s_barrier();
    __builtin_amdgcn_sched_barrier(0);
}

// ---------------------------------------------------------------------------
// Kernel 0: in_proj weight fp32 -> bf16 into the unused region of d_out
// (vt occupies [0,8MB); wb at [8MB,9.5MB); both dead before out_proj writes).
// ---------------------------------------------------------------------------
__global__ __launch_bounds__(256) void w_to_bf16(const float* __restrict__ W,
                                                 short* __restrict__ wb, int n)
{
    int i = (blockIdx.x * 256 + threadIdx.x) * 8;
    if (i < n) {
        f32x4 a = *(const f32x4*)(W + i);
        f32x4 b = *(const f32x4*)(W + i + 4);
        s16x8 o;
        o[0] = f2bf(a[0]); o[1] = f2bf(a[1]); o[2] = f2bf(a[2]); o[3] = f2bf(a[3]);
        o[4] = f2bf(b[0]); o[5] = f2bf(b[1]); o[6] = f2bf(b[2]); o[7] = f2bf(b[3]);
        *(s16x8*)(wb + i) = o;
    }
}

// ---------------------------------------------------------------------------
// BT-GEMM mainloop (r11/r13/r15-proven): BK=64, double-buffered 64KB LDS,
// 1 barrier/step, 16 MFMA/wave/step, 2-deep register pipeline +
// barrier_fast; fragment-linear swizzled LDS (0 read/write conflicts).
// Session lessons encoded here:
//  r14: no occupancy forcing — unified VGPR+AGPR demand (~92) can't fit the
//       64-reg budget 8 waves/SIMD needs; forcing spills to scratch (12x HBM).
//  r16: no global_load_lds for these operands — its linear-LDS-dest
//       constraint pushes the fragment permutation onto the global source,
//       which fragments W's row-major reads (uncoalesced DMA cost > saved
//       ds_writes; qkv 43->48.5).
// ---------------------------------------------------------------------------
template<int AF32, int BF32>
__device__ __forceinline__ void gemm_mainloop(const void* __restrict__ Ag,
                                              const void* __restrict__ Bg,
                                              short* sA, short* sB,
                                              f32x4 acc[2][4], int ld, int Klen)
{
    const int tid  = threadIdx.x;          // 0..511
    const int lane = tid & 63;
    const int wv   = tid >> 6;             // 0..7
    const int lsw  = lane ^ ((lane >> 3) & 7);
    const int amt  = (wv >> 1) * 2;        // A m-tile base (0,2,4,6)
    const int bnt  = (wv & 1) * 4;         // B n-tile base (0,4)

    const int srow = tid >> 3, qd = tid & 7;   // rows srow, srow+64; chunk qd
    const int offL = (qd >> 2) * 4096
                   + swzs((srow >> 4) * 64 + (qd & 3) * 16 + (srow & 15)) * 8;
    const int offH = (qd >> 2) * 4096
                   + swzs(((srow >> 4) + 4) * 64 + (qd & 3) * 16 + (srow & 15)) * 8;

    f32x4 aF0[4], aF1[4], bF0[4], bF1[4];      // fp32: 2 rows x 8 floats
    s16x8 aH0[2], aH1[2], bH0[2], bH1[2];      // bf16: 2 rows x 8 shorts

    auto loadX = [&](const void* G, int kt, f32x4 fr[4], s16x8 hr[2], int F32) {
        if (F32) {
            const float* g = (const float*)G + (size_t)srow * ld + kt + qd * 8;
            fr[0] = *(const f32x4*)g;
            fr[1] = *(const f32x4*)(g + 4);
            fr[2] = *(const f32x4*)(g + (size_t)64 * ld);
            fr[3] = *(const f32x4*)(g + (size_t)64 * ld + 4);
        } else {
            const short* g = (const short*)G + (size_t)srow * ld + kt + qd * 8;
            hr[0] = *(const s16x8*)g;
            hr[1] = *(const s16x8*)(g + (size_t)64 * ld);
        }
    };
    auto commitX = [&](short* s, f32x4 fr[4], s16x8 hr[2], int F32) {
        if (F32) {
            s16x8 o;
            o[0] = f2bf_fast(fr[0][0]); o[1] = f2bf_fast(fr[0][1]);
            o[2] = f2bf_fast(fr[0][2]); o[3] = f2bf_fast(fr[0][3]);
            o[4] = f2bf_fast(fr[1][0]); o[5] = f2bf_fast(fr[1][1]);
            o[6] = f2bf_fast(fr[1][2]); o[7] = f2bf_fast(fr[1][3]);
            *(s16x8*)(s + offL) = o;
            o[0] = f2bf_fast(fr[2][0]); o[1] = f2bf_fast(fr[2][1]);
            o[2] = f2bf_fast(fr[2][2]); o[3] = f2bf_fast(fr[2][3]);
            o[4] = f2bf_fast(fr[3][0]); o[5] = f2bf_fast(fr[3][1]);
            o[6] = f2bf_fast(fr[3][2]); o[7] = f2bf_fast(fr[3][3]);
            *(s16x8*)(s + offH) = o;
        } else {
            *(s16x8*)(s + offL) = hr[0];
            *(s16x8*)(s + offH) = hr[1];
        }
    };
    auto compute = [&](const short* sAc, const short* sBc) {
#pragma unroll
        for (int h = 0; h < 2; ++h) {      // two K=32 halves
            s16x8 a[2], b[4];
#pragma unroll
            for (int i = 0; i < 2; ++i)
                a[i] = *(const s16x8*)(sAc + h * 4096 + ((amt + i) * 64 + lsw) * 8);
#pragma unroll
            for (int j = 0; j < 4; ++j)
                b[j] = *(const s16x8*)(sBc + h * 4096 + ((bnt + j) * 64 + lsw) * 8);
#pragma unroll
            for (int i = 0; i < 2; ++i)
#pragma unroll
                for (int j = 0; j < 4; ++j)
                    acc[i][j] = __builtin_amdgcn_mfma_f32_16x16x32_bf16(a[i], b[j], acc[i][j], 0, 0, 0);
        }
    };

    // prologue: steps 0 and 64 in flight; step 0 committed to buf0
    loadX(Ag, 0, aF0, aH0, AF32);  loadX(Bg, 0, bF0, bH0, BF32);
    loadX(Ag, 64, aF1, aH1, AF32); loadX(Bg, 64, bF1, bH1, BF32);
    commitX(sA, aF0, aH0, AF32); commitX(sB, bF0, bH0, BF32);
    barrier_fast();

    for (int kt = 0; kt < Klen; kt += 128) {
        const int k2 = (kt + 128 < Klen) ? kt + 128 : 0;   // wrap: harmless dead load
        loadX(Ag, k2, aF0, aH0, AF32); loadX(Bg, k2, bF0, bH0, BF32);
        compute(sA, sB);
        commitX(sA + 8192, aF1, aH1, AF32); commitX(sB + 8192, bF1, bH1, BF32);
        barrier_fast();
        const int k3 = (kt + 192 < Klen) ? kt + 192 : 0;
        loadX(Ag, k3, aF1, aH1, AF32); loadX(Bg, k3, bF1, bH1, BF32);
        compute(sA + 8192, sB + 8192);
        commitX(sA, aF0, aH0, AF32); commitX(sB, bF0, bH0, BF32);
        barrier_fast();
    }
}

// ---------------------------------------------------------------------------
// Kernel 1 (r13/r15-proven): fused QKV projection.  A = X fp32, B = wb bf16.
// ---------------------------------------------------------------------------
__global__ __launch_bounds__(512, 4) void qkv_proj(const float* __restrict__ query,
                                                   const float* __restrict__ key,
                                                   const float* __restrict__ value,
                                                   const short* __restrict__ wb,
                                                   const float* __restrict__ bias,
                                                   short* __restrict__ q,
                                                   short* __restrict__ k,
                                                   short* __restrict__ vt)
{
    __shared__ __align__(16) short smem[32768];   // 64KB: A dbuf | B dbuf
    short* sA = smem;            // 2 x 8192
    short* sB = smem + 16384;    // 2 x 8192

    const int z = blockIdx.z;
    const float* X  = (z == 0) ? query : (z == 1) ? key : value;
    const short* Wz = wb   + (z == 2 ? (size_t)1024 * EMB : 0);
    const float* bz = bias + (z == 2 ? 1024 : 0);
    const float scale = (z == 0) ? 0.125f * 1.44269504f : 1.0f;

    const int blockM = blockIdx.x * 128, blockN = blockIdx.y * 128;

    f32x4 acc[2][4];
#pragma unroll
    for (int i = 0; i < 2; ++i)
#pragma unroll
        for (int j = 0; j < 4; ++j)
            acc[i][j] = (f32x4){0.f, 0.f, 0.f, 0.f};

    gemm_mainloop<1, 0>(X + (size_t)blockM * EMB, Wz + (size_t)blockN * EMB,
                        sA, sB, acc, EMB, EMB);

    const int tid = threadIdx.x, lane = tid & 63, wv = tid >> 6;
    const int l15 = lane & 15, quad = lane >> 4;
    const int wm = (wv >> 1) * 32, wn = (wv & 1) * 64;

    // ---- stage C-tile into LDS in output order (bf16, RNE) ----
#pragma unroll
    for (int j = 0; j < 4; ++j) {
        int colL = wn + j * 16 + l15;          // 0..127
        float bval = bz[blockN + colL];
        int hL = colL >> 6, hd = colL & 63;
#pragma unroll
        for (int i = 0; i < 2; ++i) {
#pragma unroll
            for (int r = 0; r < 4; ++r) {
                int rowL = wm + i * 16 + quad * 4 + r;   // 0..127
                int b = rowL & 3, sp = rowL >> 2;
                float val = (acc[i][j][r] + bval) * scale;
                int idx;
                if (z == 2) {
                    int R = (b * 2 + hL) * 64 + hd;
                    idx = R * 32 + (((sp >> 3) ^ (R & 3)) << 3) + (sp & 7);
                } else {
                    idx = ((b * 2 + hL) * 32 + sp) * 64 + hd;
                }
                smem[idx] = f2bf(val);
            }
        }
    }
    barrier_fast();

    // ---- coalesced stores: thread t owns shorts [t*32, t*32+32) ----
    if (z == 2) {
        int R = tid;
        int b = tid >> 7, hL = (tid >> 6) & 1, hd = tid & 63;
        int h = (blockN >> 6) + hL;
        short* dst = vt + ((size_t)(b * 8 + h) * 64 + hd) * 2048 + (blockM >> 2);
#pragma unroll
        for (int u = 0; u < 4; ++u)
            ((s16x8*)dst)[u] = *(const s16x8*)(smem + R * 32 + ((u ^ (R & 3)) << 3));
    } else {
        const s16x8* src = (const s16x8*)(smem + tid * 32);
        int b = tid >> 7, hL = (tid >> 6) & 1;
        int sp = (tid >> 1) & 31, hdh = (tid & 1) * 32;
        int h = (blockN >> 6) + hL;
        short* dstp = (z == 0) ? q : k;
        short* dst = dstp + ((size_t)(b * 8 + h) * 2048 + (blockM >> 2) + sp) * 64 + hdh;
#pragma unroll
        for (int u = 0; u < 4; ++u) ((s16x8*)dst)[u] = src[u];
    }
}

// ---------------------------------------------------------------------------
// Kernel 2 (r12/r13/r15-proven 42.5us): flash attention — 512 threads / 256
// blocks (grid 32x8), 8 waves share one 64KB K/V double-buffer.
// Q pre-scaled by log2(e)/8 so p = exp2(s').
// ---------------------------------------------------------------------------
__global__ __launch_bounds__(512, 2) void flash_attn(const short* __restrict__ q,
                                                     const short* __restrict__ k,
                                                     const short* __restrict__ vt,
                                                     short* __restrict__ attn)
{
    __shared__ __align__(16) short sK[2][8192];   // [buf][sub(4096) | half(2048) | slots]
    __shared__ __align__(16) short sV[2][8192];
    const int bh = blockIdx.x;            // fast grid dim -> XCD locality
    const int q0 = blockIdx.y * 256;
    const int tid = threadIdx.x, wv = tid >> 6, lane = tid & 63;
    const int l15 = lane & 15, quad = lane >> 4;
    const int lsw = lane ^ ((lane >> 3) & 7);

    // Q fragments: 2 sub-tiles (qr) x 2 K-halves; rows q0 + wv*32 + qr*16 + l15
    s16x8 qf[2][2];
#pragma unroll
    for (int qr = 0; qr < 2; ++qr) {
        const short* qp = q + ((size_t)(bh * 2048 + q0 + wv * 32 + qr * 16 + l15)) * 64 + quad * 8;
        qf[qr][0] = *(const s16x8*)qp;
        qf[qr][1] = *(const s16x8*)(qp + 32);
    }

    const short* kg = k  + (size_t)bh * 2048 * 64;   // + (kt+key)*64 + hd
    const short* vg = vt + (size_t)bh * 64 * 2048;   // + hd*2048 + kt + key

    // staging: thread (tL = tid&255, sub = tid>>8); rk = tL>>2, qd = tL&3
    const int tL = tid & 255, sub = tid >> 8;
    const int rk = tL >> 2, qd = tL & 3;
    const int pr = (rk & 35) | ((rk & 24) >> 1) | ((rk & 4) << 2);
    const int kw0 = sub * 4096 + swzs((pr >> 4) * 64 + qd * 16 + (pr & 15)) * 8;
    const int vw0 = sub * 4096 + swzs((rk >> 4) * 64 + qd * 16 + (rk & 15)) * 8;
    const short* kgt = kg + (size_t)(sub * 64 + rk) * 64 + qd * 8;
    const short* vgt = vg + (size_t)rk * 2048 + sub * 64 + qd * 8;

    f32x4 o[2][4];
    float ls[2][4];
#pragma unroll
    for (int qr = 0; qr < 2; ++qr)
#pragma unroll
        for (int i = 0; i < 4; ++i) { o[qr][i] = (f32x4){0.f, 0.f, 0.f, 0.f}; ls[qr][i] = 0.f; }

    // staging regs: this thread's sub only
    s16x8 kA, kB, vA, vB;
    auto loadT = [&](int kt) {           // kt = base of 128-key tile
        kA = *(const s16x8*)(kgt + (size_t)kt * 64);
        kB = *(const s16x8*)(kgt + (size_t)kt * 64 + 32);
        vA = *(const s16x8*)(vgt + kt);
        vB = *(const s16x8*)(vgt + kt + 32);
    };
    auto commitT = [&](int buf) {
        *(s16x8*)(sK[buf] + kw0)        = kA;
        *(s16x8*)(sK[buf] + kw0 + 2048) = kB;
        *(s16x8*)(sV[buf] + vw0)        = vA;
        *(s16x8*)(sV[buf] + vw0 + 2048) = vB;
    };
    auto computeQK = [&](const short* Kc, f32x4 sc[2][4]) {
#pragma unroll
        for (int ct = 0; ct < 4; ++ct) {
            s16x8 kf0 = *(const s16x8*)(Kc + (ct * 64 + lsw) * 8);
            s16x8 kf1 = *(const s16x8*)(Kc + (ct * 64 + lsw) * 8 + 2048);
#pragma unroll
            for (int qr = 0; qr < 2; ++qr) {
                f32x4 c = (f32x4){0.f, 0.f, 0.f, 0.f};
                c = __builtin_amdgcn_mfma_f32_16x16x32_bf16(kf0, qf[qr][0], c, 0, 0, 0);
                c = __builtin_amdgcn_mfma_f32_16x16x32_bf16(kf1, qf[qr][1], c, 0, 0, 0);
                sc[qr][ct] = c;
            }
        }
    };
    auto softmaxPV = [&](f32x4 sc[2][4], const short* Vc) {
        s16x8 pf[2][2];
#pragma unroll
        for (int qr = 0; qr < 2; ++qr)
#pragma unroll
            for (int c = 0; c < 2; ++c)
#pragma unroll
                for (int h = 0; h < 2; ++h)
#pragma unroll
                    for (int r = 0; r < 4; ++r) {
                        float p = EXP2F(sc[qr][2 * c + h][r]);
                        ls[qr][r] += p;
                        pf[qr][c][h * 4 + r] = f2bf_cvt(p);
                    }
#pragma unroll
        for (int nt = 0; nt < 4; ++nt)
#pragma unroll
            for (int c = 0; c < 2; ++c) {
                s16x8 vf = *(const s16x8*)(Vc + ((c * 4 + nt) * 64 + lsw) * 8);
#pragma unroll
                for (int qr = 0; qr < 2; ++qr)
                    o[qr][nt] = __builtin_amdgcn_mfma_f32_16x16x32_bf16(pf[qr][c], vf, o[qr][nt], 0, 0, 0);
            }
    };

    loadT(0);
    commitT(0);
    __syncthreads();

    int cur = 0;
    for (int kt = 0; kt < 2048; kt += 128) {
        loadT((kt + 128) & 2047);        // wraps on last iter (harmless)

        f32x4 sc0[2][4], sc1[2][4];
        computeQK(sK[cur], sc0);
        computeQK(sK[cur] + 4096, sc1);  // independent of sc0's softmax
        softmaxPV(sc0, sV[cur]);         // VALU overlaps sc1's MFMAs
        softmaxPV(sc1, sV[cur] + 4096);  // sub1 softmax overlaps sub0 PV

        commitT(cur ^ 1);
        __syncthreads();
        cur ^= 1;
    }

    const int b = bh >> 3, h = bh & 7;
#pragma unroll
    for (int qr = 0; qr < 2; ++qr) {
        float s = ls[qr][0] + ls[qr][1] + ls[qr][2] + ls[qr][3];
        s += __shfl_xor(s, 16, 64);
        s += __shfl_xor(s, 32, 64);
        float sinv = 1.0f / s;
        float inv[4];
#pragma unroll
        for (int r = 0; r < 4; ++r)
            inv[r] = __shfl(sinv, quad * 20 + r, 64);
#pragma unroll
        for (int r = 0; r < 4; ++r) {
            int srow = q0 + wv * 32 + qr * 16 + quad * 4 + r;
#pragma unroll
            for (int nt = 0; nt < 4; ++nt)
                attn[(size_t)(srow * 4 + b) * 512 + h * 64 + nt * 16 + l15] = f2bf(o[qr][nt][r] * inv[r]);
        }
    }
}

// ---------------------------------------------------------------------------
// Kernel 3 (r11/r13/r15-proven): output projection, single dispatch, BK=64,
// double-buffered.  A = attn (bf16 scratch), B = W (fp32), out FP32.
// ---------------------------------------------------------------------------
__global__ __launch_bounds__(512, 4) void out_proj(const short* __restrict__ attn,
                                                   const float* __restrict__ W,
                                                   const float* __restrict__ bias,
                                                   float* __restrict__ out)
{
    __shared__ __align__(16) short smem[32768];   // 64KB: A dbuf | B dbuf
    short* sA = smem;
    short* sB = smem + 16384;
    const int blockM = blockIdx.x * 128, blockN = blockIdx.y * 128;

    f32x4 acc[2][4];
#pragma unroll
    for (int i = 0; i < 2; ++i)
#pragma unroll
        for (int j = 0; j < 4; ++j)
            acc[i][j] = (f32x4){0.f, 0.f, 0.f, 0.f};

    gemm_mainloop<0, 1>(attn + (size_t)blockM * EMB, W + (size_t)blockN * EMB,
                        sA, sB, acc, EMB, EMB);

    const int tid = threadIdx.x, lane = tid & 63, wv = tid >> 6;
    const int l15 = lane & 15, quad = lane >> 4;
    const int wm = (wv >> 1) * 32, wn = (wv & 1) * 64;

#pragma unroll
    for (int j = 0; j < 4; ++j) {
        int col = blockN + wn + j * 16 + l15;
        float bval = bias[col];
#pragma unroll
        for (int i = 0; i < 2; ++i) {
#pragma unroll
            for (int r = 0; r < 4; ++r) {
                int row = blockM + wm + i * 16 + quad * 4 + r;
                out[(size_t)row * 512 + col] = acc[i][j][r] + bval;
            }
        }
    }
}

// ---------------------------------------------------------------------------
// Dtype contract: inputs FP32, output FP32. Internals bf16.
// 4 dispatches:
//   w_to_bf16:  in_proj W fp32 -> bf16 wb (d_out+8MB, dead before out_proj)
//   qkv_proj:   fp32 X + bf16 W -> bf16 q,k (ws) + V^T into d_out[0..8MB)
//   flash_attn: q, k, d_out(V^T) -> attn (ws+16MB)
//   out_proj:   attn + fp32 W_out -> d_out (fp32 final, overwrites scratch)
// ---------------------------------------------------------------------------
extern "C" void kernel_launch(void* const* d_in, const int* in_sizes, int n_in,
                              void* d_out, int out_size, void* d_ws, size_t ws_size,
                              hipStream_t stream)
{
    const float* query = (const float*)d_in[0];
    const float* key   = (const float*)d_in[1];
    const float* value = (const float*)d_in[2];
    const float* ipw   = (const float*)d_in[3];   // (1536, 512)
    const float* ipb   = (const float*)d_in[4];   // (1536,)
    const float* opw   = (const float*)d_in[5];   // (512, 512)
    const float* opb   = (const float*)d_in[6];   // (512,)
    float* out = (float*)d_out;

    const size_t NELEM = (size_t)MROWS * EMB;     // 4,194,304 elements
    short* q    = (short*)d_ws;
    short* k    = q + NELEM;
    short* attn = k + NELEM;
    short* vt   = (short*)d_out;                  // [0 .. 8MB) of d_out
    short* wb   = (short*)d_out + NELEM;          // [8MB .. 9.5MB) of d_out

    w_to_bf16 <<<dim3(384),      256, 0, stream>>>(ipw, wb, 1536 * EMB);
    qkv_proj  <<<dim3(64, 4, 3), 512, 0, stream>>>(query, key, value, wb, ipb, q, k, vt);
    flash_attn<<<dim3(32, 8),    512, 0, stream>>>(q, k, vt, attn);
    out_proj  <<<dim3(64, 4),    512, 0, stream>>>(attn, opw, opb, out);
}